// Round 10
// baseline (212.085 us; speedup 1.0000x reference)
//
#include <hip/hip_runtime.h>
#include <hip/hip_bf16.h>
#include <stdint.h>

// Problem constants (B=2, N=2048, C=1024, H=16, D=64)
#define SL_F 0.18033688011112043f   // SCALE * log2(e): softmax in exp2 domain

typedef unsigned short u16;
typedef unsigned int u32;
typedef __attribute__((ext_vector_type(8))) short bf16x8;   // 8 bf16 = 4 VGPRs
typedef __attribute__((ext_vector_type(4))) float f32x4;

__device__ __forceinline__ u16 f2bf(float f) {
    union { float f; u32 u; } v; v.f = f;
    return (u16)((v.u + 0x7fffu + ((v.u >> 16) & 1u)) >> 16);  // RNE
}
__device__ __forceinline__ u32 pack2bf(float a, float b) {
    union { __hip_bfloat162 h; u32 u; } p;
    p.h = __float22bfloat162_rn(make_float2(a, b));
    return p.u;
}

// async global->LDS, 16B per lane; LDS dest = wave-uniform base + lane*16
__device__ __forceinline__ void gl_lds16(const u16* g, u16* l) {
    __builtin_amdgcn_global_load_lds(
        (const __attribute__((address_space(1))) u32*)g,
        (__attribute__((address_space(3))) u32*)l, 16, 0, 0);
}

// ---------------- fp32 -> bf16 TILED conversion of x, w_qkv, w_proj ---------
// Fragment-tiled layout (r9, VERIFIED -> qkv left top-5): chunk(g,kb)=1KB =
// rows g*16..+15, k kb*32..+31; slot lane = (r&15)+16*((k>>3)&3), byte (k&7)*2
// — bit-identical to gl_lds16's LDS deposit, so staging = chunk + lane*16
// (8 full 128B lines/instr vs 16-line 64B-per-line gather).
__global__ __launch_bounds__(256) void convert_k(
    const float* __restrict__ x, const float* __restrict__ w1,
    const float* __restrict__ w2,
    u16* __restrict__ xb, u16* __restrict__ w1b, u16* __restrict__ w2b)
{
    const int t = blockIdx.x * 256 + threadIdx.x;   // global slot id
    const int XA = 524288, XW1 = 393216;            // slots: 4096*128, 3072*128
    const float* src; u16* dst; int s;
    if (t < XA)            { src = x;  dst = xb;  s = t; }
    else if (t < XA + XW1) { src = w1; dst = w1b; s = t - XA; }
    else                   { src = w2; dst = w2b; s = t - XA - XW1; }
    const int c = s >> 6;                    // chunk (wave-uniform)
    const int u = s & 63;
    const int l = (u >> 2) + 16 * (u & 3);   // slot within chunk
    const int g = c >> 5, kb = c & 31;
    const int row = g * 16 + (l & 15);
    const int k0 = kb * 32 + (l >> 4) * 8;
    const float4 v0 = *(const float4*)&src[(size_t)row * 1024 + k0];
    const float4 v1 = *(const float4*)&src[(size_t)row * 1024 + k0 + 4];
    uint4 o;
    o.x = pack2bf(v0.x, v0.y); o.y = pack2bf(v0.z, v0.w);
    o.z = pack2bf(v1.x, v1.y); o.w = pack2bf(v1.z, v1.w);
    *(uint4*)&dst[((size_t)c * 64 + l) * 8] = o;
}

// ---------------- QKV GEMM: out[m,n] = sum_k A[m,k]*W[n,k] + bias ------------
// r6 proven body + 24x32 2-D grid (24%8==0 -> XCD banding + balanced scatter).
// A/B staged from tiled layout (r9, verified).
// r10 epilogue: K and V^T written in FRAGMENT-TILED chunks (16x32, slot order
// = gl_lds16 deposit) so attn's K/V staging becomes contiguous — same
// mechanism as r9's input fix, applied to the qkv->attn interface.
//   K  chunk(n,d) = (n>>4)*2 + (d>>5);  slot = (n&15) + 16*((d>>3)&3), byte d&7
//   V^T chunk(d,n) = (n>>7)*16 + (d>>4)*4 + ((n>>5)&3); slot = (d&15) + 16*((n>>3)&3), byte n&7
// Q stays row-major [B,H,N,D] (attn reads it per-lane into registers).
__global__ __launch_bounds__(256) void qkv_gemm(
    const u16* __restrict__ A, const u16* __restrict__ Bw,
    const float* __restrict__ bias,
    u16* __restrict__ Qb, u16* __restrict__ Kb, u16* __restrict__ VTb)
{
    __shared__ __align__(16) u16 Al[2][8 * 512];
    __shared__ __align__(16) u16 Bl[2][8 * 512];
    const int tid = threadIdx.x;
    const int lane = tid & 63;
    const int w = tid >> 6;
    const int la = lane & 15, qd = lane >> 4;
    const int m0 = blockIdx.y * 128;
    const int n0 = blockIdx.x * 128;
    const int wm = (w >> 1) * 64, wn = (w & 1) * 64;

    // tiled chunk bases: chunk linear = group*32 + kb, 512 u16 each
    const u16* Ag0 = A + ((size_t)((m0 >> 4) + 2 * w) * 32) * 512 + lane * 8;
    const u16* Ag1 = Ag0 + 32 * 512;
    const u16* Bg0 = Bw + ((size_t)((n0 >> 4) + 2 * w) * 32) * 512 + lane * 8;
    const u16* Bg1 = Bg0 + 32 * 512;

    auto stage = [&](int k0, int b) {
        const size_t ko = (size_t)(k0 >> 5) * 512;
        gl_lds16(Ag0 + ko, &Al[b][(2 * w) * 512]);
        gl_lds16(Ag1 + ko, &Al[b][(2 * w + 1) * 512]);
        gl_lds16(Bg0 + ko, &Bl[b][(2 * w) * 512]);
        gl_lds16(Bg1 + ko, &Bl[b][(2 * w + 1) * 512]);
    };

    f32x4 acc[4][4] = {};
    int buf = 0;
    stage(0, 0);

    for (int k0 = 0; k0 < 1024; k0 += 32) {
        __syncthreads();                       // drains prev prefetch (vmcnt 0)
        if (k0 + 32 < 1024) stage(k0 + 32, buf ^ 1);

        bf16x8 af[4], bfr[4];
#pragma unroll
        for (int i = 0; i < 4; i++)
            af[i] = *(const bf16x8*)&Al[buf][(((unsigned)wm >> 4) + i) * 512 + lane * 8];
#pragma unroll
        for (int j = 0; j < 4; j++)
            bfr[j] = *(const bf16x8*)&Bl[buf][(((unsigned)wn >> 4) + j) * 512 + lane * 8];
#pragma unroll
        for (int i = 0; i < 4; i++)
#pragma unroll
            for (int j = 0; j < 4; j++)
                acc[i][j] = __builtin_amdgcn_mfma_f32_16x16x32_bf16(
                    af[i], bfr[j], acc[i][j], 0, 0, 0);
        buf ^= 1;
    }

    // Epilogue. C/D layout: col = lane&15, row = (lane>>4)*4 + reg  [m89-verified]
#pragma unroll
    for (int j = 0; j < 4; j++) {
        const int col = n0 + wn + j * 16 + la;
        const float bv = bias[col];
        const int t = col >> 10, hd = col & 1023, h = hd >> 6, d = hd & 63;
#pragma unroll
        for (int i = 0; i < 4; i++)
#pragma unroll
            for (int r = 0; r < 4; r++) {
                const int row = m0 + wm + i * 16 + qd * 4 + r;
                const int b = row >> 11, n = row & 2047;
                const int bh = b * 16 + h;
                const u16 val = f2bf(acc[i][j][r] + bv);
                if (t == 0)
                    Qb[((size_t)bh * 2048 + n) * 64 + d] = val;
                else if (t == 1)
                    Kb[((size_t)bh * 256 + (n >> 4) * 2 + (d >> 5)) * 512
                       + ((n & 15) + 16 * ((d >> 3) & 3)) * 8 + (d & 7)] = val;
                else
                    VTb[((size_t)bh * 256 + (n >> 7) * 16 + (d >> 4) * 4 + ((n >> 5) & 3)) * 512
                        + ((d & 15) + 16 * ((n >> 3) & 3)) * 8 + (n & 7)] = val;
            }
    }
}

// ---------------- proj GEMM, BK=64; A and B both from tiled layouts ----------
// M=4096, N=1024, K=1024; tile 128x64, 2-D grid 16x32. r10: A (= Ob, now
// written tiled by attn) staged contiguously; B (wprojb) tiled since r9.
__global__ __launch_bounds__(256) void proj_gemm(
    const u16* __restrict__ A, const u16* __restrict__ Bw,
    const float* __restrict__ bias, float* __restrict__ Out)
{
    __shared__ __align__(16) u16 Al[2][16 * 512];   // 32 KB
    __shared__ __align__(16) u16 Bl[2][8 * 512];    // 16 KB
    const int tid = threadIdx.x;
    const int lane = tid & 63;
    const int w = tid >> 6;
    const int la = lane & 15, qd = lane >> 4;
    const int K = 1024;
    const int m0 = blockIdx.y * 128;
    const int n0 = blockIdx.x * 64;
    const int wm = (w >> 1) * 64, wn = (w & 1) * 32;

    // A tiled: chunk(m,k) = (m>>4)*32 + (k>>5); wave w owns ck=4w+t ->
    // m-group g=ck>>1, k-half h=ck&1 within the BK=64 step.
    const u16* Ab[4];
#pragma unroll
    for (int t = 0; t < 4; t++) {
        const int ck = 4 * w + t, g = ck >> 1, h = ck & 1;
        Ab[t] = A + (((size_t)(m0 >> 4) + g) * 32 + h) * 512 + lane * 8;
    }
    // B tiled: wave w owns n-group (n0>>4)+w, k-halves t=0,1
    const u16* Bg = Bw + ((size_t)((n0 >> 4) + w) * 32) * 512 + lane * 8;

    auto stage = [&](int k0, int b) {
#pragma unroll
        for (int t = 0; t < 4; t++)
            gl_lds16(Ab[t] + (size_t)(k0 >> 5) * 512, &Al[b][(4 * w + t) * 512]);
#pragma unroll
        for (int t = 0; t < 2; t++)
            gl_lds16(Bg + (size_t)((k0 >> 5) + t) * 512, &Bl[b][(2 * w + t) * 512]);
    };

    f32x4 acc[4][2] = {};
    int buf = 0;
    stage(0, 0);

    for (int k0 = 0; k0 < K; k0 += 64) {
        __syncthreads();                       // drains prev prefetch (vmcnt 0)
        if (k0 + 64 < K) stage(k0 + 64, buf ^ 1);

        bf16x8 af[4][2], bfr[2][2];
#pragma unroll
        for (int i = 0; i < 4; i++) {
            const int g = ((unsigned)wm >> 4) + i;
#pragma unroll
            for (int h = 0; h < 2; h++)
                af[i][h] = *(const bf16x8*)&Al[buf][(g * 2 + h) * 512 + lane * 8];
        }
#pragma unroll
        for (int j = 0; j < 2; j++) {
            const int g = ((unsigned)wn >> 4) + j;
#pragma unroll
            for (int h = 0; h < 2; h++)
                bfr[j][h] = *(const bf16x8*)&Bl[buf][(g * 2 + h) * 512 + lane * 8];
        }
#pragma unroll
        for (int i = 0; i < 4; i++)
#pragma unroll
            for (int j = 0; j < 2; j++) {
                f32x4 c = acc[i][j];
                c = __builtin_amdgcn_mfma_f32_16x16x32_bf16(af[i][0], bfr[j][0], c, 0, 0, 0);
                c = __builtin_amdgcn_mfma_f32_16x16x32_bf16(af[i][1], bfr[j][1], c, 0, 0, 0);
                acc[i][j] = c;
            }
        buf ^= 1;
    }

    // Epilogue (fp32 out + bias). C/D layout: col = lane&15, row = qd*4 + r.
#pragma unroll
    for (int j = 0; j < 2; j++) {
        const int col = n0 + wn + j * 16 + la;
        const float bv = bias[col];
#pragma unroll
        for (int i = 0; i < 4; i++)
#pragma unroll
            for (int r = 0; r < 4; r++) {
                const int row = m0 + wm + i * 16 + qd * 4 + r;
                Out[(size_t)row * 1024 + col] = acc[i][j][r] + bv;
            }
    }
}

// ---------------- causal flash attention, LDS-staged, j-step 128 -------------
// r10: K/V staged from TILED global layouts — each gl_lds16 reads a contiguous
// 1KB chunk (was 16 rows x 64B at 128B/4KB stride = the exact gather pattern
// whose fix took qkv out of the top-5 in r9). attn's staged 278MB ran at
// 5.9 TB/s = the gather ceiling; contiguous should ~2x it. LDS image is
// bit-identical -> QK^T/softmax/PV loops untouched.
// Output Ob written in proj-A-tiled layout (each wave owns one m-row of the
// scrambled [4096,1024] view: m = bh*128 + (q0>>4), k = (qd*4+r)*64+c2*16+la).
__global__ __launch_bounds__(256) void attn_k(
    const u16* __restrict__ Qb, const u16* __restrict__ Kb,
    const u16* __restrict__ VTb, u16* __restrict__ Ob)
{
    __shared__ __align__(16) u16 Kl[2][16 * 512];   // 32 KB: chunk ck=c*2+h
    __shared__ __align__(16) u16 Vl[2][16 * 512];   // 32 KB: chunk cv=c2*4+kc
    __shared__ __align__(16) u16 Pl[4][16 * 72];    // per-wave P, stride 72
    const int bh = blockIdx.x & 31;
    const int pair = blockIdx.x >> 5;               // 0..15
    const int tid = threadIdx.x;
    const int lane = tid & 63;
    const int w = tid >> 6;
    const int la = lane & 15, qd = lane >> 4;

    // tiled K/V chunk bases (256 chunks of 512 u16 per bh)
    const u16* Kbh = Kb + (size_t)bh * 256 * 512 + lane * 8;
    const u16* Vbh = VTb + (size_t)bh * 256 * 512 + lane * 8;
    u16* Pw = &Pl[w][0];

    // stage: wave w stages K chunks 4w..4w+3 and V chunks 4w..4w+3 of a j128
    // tile. K chunk index = j0>>3 + ck; V chunk index = (j0>>7)*16 + ck.
    auto stage = [&](int j0, int b) {
#pragma unroll
        for (int t = 0; t < 4; t++) {
            const int ck = 4 * w + t;
            gl_lds16(Kbh + (size_t)((j0 >> 3) + ck) * 512, &Kl[b][ck * 512]);
            gl_lds16(Vbh + (size_t)((j0 >> 7) * 16 + ck) * 512, &Vl[b][ck * 512]);
        }
    };

    int buf = 0;
    stage(0, 0);                                    // prologue for first tile

    for (int half = 0; half < 2; half++) {
        const int tile = (half == 0) ? pair : 31 - pair;
        const int q0 = tile * 64 + w * 16;
        const int jmax = (tile >> 1) * 128;         // last j128-tile start
        const int qrow = q0 + la;                   // this lane's q-row

        const u16* Qp = Qb + ((size_t)bh * 2048 + q0 + la) * 64 + qd * 8;
        const bf16x8 qf0 = *(const bf16x8*)Qp;
        const bf16x8 qf1 = *(const bf16x8*)(Qp + 32);

        f32x4 o[4] = {};
        float lsum = 0.f;

        for (int j0 = 0; j0 <= jmax; j0 += 128) {
            __syncthreads();   // drains prev prefetch (vmcnt 0, all waves)

            const int nj = (j0 + 128 <= jmax) ? (j0 + 128) : ((half == 0) ? 0 : -1);
            if (nj >= 0) stage(nj, buf ^ 1);

            // S^T = K Q^T : 8 j-subtiles; D[row=j (qd*4+r), col=q (la)]
            f32x4 s[8];
#pragma unroll
            for (int c = 0; c < 8; c++) {
                f32x4 z = {};
                const bf16x8 kf0 = *(const bf16x8*)&Kl[buf][(c * 2 + 0) * 512 + lane * 8];
                const bf16x8 kf1 = *(const bf16x8*)&Kl[buf][(c * 2 + 1) * 512 + lane * 8];
                z = __builtin_amdgcn_mfma_f32_16x16x32_bf16(kf0, qf0, z, 0, 0, 0);
                z = __builtin_amdgcn_mfma_f32_16x16x32_bf16(kf1, qf1, z, 0, 0, 0);
                s[c] = z;
            }

            // p = exp2(s * SL); causal mask only on the diagonal-containing tile
            if (j0 == jmax) {
#pragma unroll
                for (int c = 0; c < 8; c++)
#pragma unroll
                    for (int r = 0; r < 4; r++) {
                        const int j = j0 + c * 16 + qd * 4 + r;
                        float v = s[c][r] * SL_F;
                        v = (j > qrow) ? -1e30f : v;
                        s[c][r] = __builtin_amdgcn_exp2f(v);
                    }
            } else {
#pragma unroll
                for (int c = 0; c < 8; c++)
#pragma unroll
                    for (int r = 0; r < 4; r++)
                        s[c][r] = __builtin_amdgcn_exp2f(s[c][r] * SL_F);
            }
#pragma unroll
            for (int c = 0; c < 8; c++)
#pragma unroll
                for (int r = 0; r < 4; r++)
                    lsum += s[c][r];

            // PV in two j-64 halves, reusing the per-wave P buffer (same-wave
            // DS ops are in-order: the hh=1 writes cannot pass hh=0 reads)
#pragma unroll
            for (int hh = 0; hh < 2; hh++) {
#pragma unroll
                for (int c = 0; c < 4; c++) {
                    uint2 pw;
                    pw.x = pack2bf(s[hh * 4 + c][0], s[hh * 4 + c][1]);
                    pw.y = pack2bf(s[hh * 4 + c][2], s[hh * 4 + c][3]);
                    *(uint2*)&Pw[la * 72 + c * 16 + qd * 4] = pw;
                }
                const bf16x8 pf0 = *(const bf16x8*)&Pw[la * 72 + qd * 8];
                const bf16x8 pf1 = *(const bf16x8*)&Pw[la * 72 + 32 + qd * 8];
#pragma unroll
                for (int c2 = 0; c2 < 4; c2++) {
                    const bf16x8 vf0 = *(const bf16x8*)&Vl[buf][(c2 * 4 + hh * 2 + 0) * 512 + lane * 8];
                    const bf16x8 vf1 = *(const bf16x8*)&Vl[buf][(c2 * 4 + hh * 2 + 1) * 512 + lane * 8];
                    o[c2] = __builtin_amdgcn_mfma_f32_16x16x32_bf16(pf0, vf0, o[c2], 0, 0, 0);
                    o[c2] = __builtin_amdgcn_mfma_f32_16x16x32_bf16(pf1, vf1, o[c2], 0, 0, 0);
                }
            }
            buf ^= 1;
        }

        // reduce l across the 4 quads (lane la holds row la's partials)
        lsum += __shfl_xor(lsum, 16, 64);
        lsum += __shfl_xor(lsum, 32, 64);
        float rinv[4];
#pragma unroll
        for (int r = 0; r < 4; r++)
            rinv[r] = 1.0f / __shfl(lsum, qd * 4 + r, 64);

        // write Ob in proj-A-tiled layout: m = bh*128 + (q0>>4) (wave-uniform),
        // k = (qd*4+r)*64 + c2*16 + la; chunk=(m>>4)*32+(k>>5),
        // slot=(m&15)+16*((k>>3)&3), byte k&7.
        const int m = bh * 128 + (q0 >> 4);
        u16* Ot = Ob + ((size_t)(m >> 4) * 32) * 512;
        const int mm = m & 15;
#pragma unroll
        for (int c2 = 0; c2 < 4; c2++)
#pragma unroll
            for (int r = 0; r < 4; r++) {
                const int kk5 = (qd * 4 + r) * 2 + (c2 >> 1);
                const int s3 = (c2 * 2 + (la >> 3)) & 3;
                Ot[(size_t)kk5 * 512 + (mm + 16 * s3) * 8 + (la & 7)] =
                    f2bf(o[c2][r] * rinv[r]);
            }
    }
}

// ---------------- launch -----------------------------------------------------
extern "C" void kernel_launch(void* const* d_in, const int* in_sizes, int n_in,
                              void* d_out, int out_size, void* d_ws, size_t ws_size,
                              hipStream_t stream)
{
    const float* x     = (const float*)d_in[0];
    // d_in[1] = attention_mask: structurally causal tril; enforced analytically.
    const float* wqkv  = (const float*)d_in[2];
    const float* bqkv  = (const float*)d_in[3];
    const float* wproj = (const float*)d_in[4];
    const float* bproj = (const float*)d_in[5];
    float* out = (float*)d_out;

    // workspace layout (u16 units), ~50 MB total
    u16* ws     = (u16*)d_ws;
    u16* xb     = ws;                       // 4096*1024   (tiled)
    u16* wqkvb  = xb + 4096 * 1024;         // 3072*1024   (tiled)
    u16* wprojb = wqkvb + 3072 * 1024;      // 1024*1024   (tiled)
    u16* Qb     = wprojb + 1024 * 1024;     // 32*2048*64  [B,H,N,D] row-major
    u16* Kb     = Qb + 32 * 2048 * 64;      // 32*256 chunks (tiled)
    u16* VTb    = Kb + 32 * 2048 * 64;      // 32*256 chunks (tiled)
    u16* Ob     = VTb + 32 * 2048 * 64;     // 8192 chunks (proj-A tiled)

    convert_k<<<dim3(4096), dim3(256), 0, stream>>>(
        x, wqkv, wproj, xb, wqkvb, wprojb);

    // qkv: 128x128 tile, 2-D grid 24x32 (XCD banding + balanced scatter)
    qkv_gemm<<<dim3(24, 32), dim3(256), 0, stream>>>(
        xb, wqkvb, bqkv, Qb, Kb, VTb);

    attn_k<<<dim3(512), dim3(256), 0, stream>>>(Qb, Kb, VTb, Ob);

    // proj: 128x64 tile, BK=64, 2-D grid 16x32
    proj_gemm<<<dim3(16, 32), dim3(256), 0, stream>>>(
        Ob, wprojb, bproj, out);
}

// Round 11
// 188.619 us; speedup vs baseline: 1.1244x; 1.1244x over previous
//
#include <hip/hip_runtime.h>
#include <hip/hip_bf16.h>
#include <stdint.h>

// Problem constants (B=2, N=2048, C=1024, H=16, D=64)
#define SL_F 0.18033688011112043f   // SCALE * log2(e): softmax in exp2 domain

typedef unsigned short u16;
typedef unsigned int u32;
typedef __attribute__((ext_vector_type(8))) short bf16x8;   // 8 bf16 = 4 VGPRs
typedef __attribute__((ext_vector_type(4))) float f32x4;

__device__ __forceinline__ u16 f2bf(float f) {
    union { float f; u32 u; } v; v.f = f;
    return (u16)((v.u + 0x7fffu + ((v.u >> 16) & 1u)) >> 16);  // RNE
}
__device__ __forceinline__ u32 pack2bf(float a, float b) {
    union { __hip_bfloat162 h; u32 u; } p;
    p.h = __float22bfloat162_rn(make_float2(a, b));
    return p.u;
}

// async global->LDS, 16B per lane; LDS dest = wave-uniform base + lane*16.
// Global src is PER-LANE: coalescing needs the 64-address SET contiguous,
// not lane-identity order (r11 insight: permuted-slot chunks).
__device__ __forceinline__ void gl_lds16(const u16* g, u16* l) {
    __builtin_amdgcn_global_load_lds(
        (const __attribute__((address_space(1))) u32*)g,
        (__attribute__((address_space(3))) u32*)l, 16, 0, 0);
}

// ---------------- fp32 -> bf16 TILED conversion of x, w_qkv, w_proj ---------
// Fragment-tiled layout (r9, VERIFIED): chunk(g,kb)=1KB, slot order =
// gl_lds16 deposit. Staging = chunk + lane*16 (8 full 128B lines/instr).
__global__ __launch_bounds__(256) void convert_k(
    const float* __restrict__ x, const float* __restrict__ w1,
    const float* __restrict__ w2,
    u16* __restrict__ xb, u16* __restrict__ w1b, u16* __restrict__ w2b)
{
    const int t = blockIdx.x * 256 + threadIdx.x;   // global slot id
    const int XA = 524288, XW1 = 393216;            // slots: 4096*128, 3072*128
    const float* src; u16* dst; int s;
    if (t < XA)            { src = x;  dst = xb;  s = t; }
    else if (t < XA + XW1) { src = w1; dst = w1b; s = t - XA; }
    else                   { src = w2; dst = w2b; s = t - XA - XW1; }
    const int c = s >> 6;                    // chunk (wave-uniform)
    const int u = s & 63;
    const int l = (u >> 2) + 16 * (u & 3);   // slot within chunk
    const int g = c >> 5, kb = c & 31;
    const int row = g * 16 + (l & 15);
    const int k0 = kb * 32 + (l >> 4) * 8;
    const float4 v0 = *(const float4*)&src[(size_t)row * 1024 + k0];
    const float4 v1 = *(const float4*)&src[(size_t)row * 1024 + k0 + 4];
    uint4 o;
    o.x = pack2bf(v0.x, v0.y); o.y = pack2bf(v0.z, v0.w);
    o.z = pack2bf(v1.x, v1.y); o.w = pack2bf(v1.z, v1.w);
    *(uint4*)&dst[((size_t)c * 64 + l) * 8] = o;
}

// ---------------- QKV GEMM: out[m,n] = sum_k A[m,k]*W[n,k] + bias ------------
// r6 proven body + 24x32 grid + r9 tiled A/B staging (all verified).
// r11 epilogue: K/V^T chunks are ROW-MAJOR interior (NOT fragment-slot order
// — that was r10's +13us mistake: 16B-granule scatters + heavy addr math).
//   K  per bh: chunk c=(n>>4)*2+(d>>5), interior u16 = (n&15)*32 + (d&31)
//   V^T per bh: chunk c=(d>>4)*64+(n>>5), interior u16 = (d&15)*32 + (n&31)
// Write coalescing == r9 row-major for K (4x32B segs/store), BETTER for V
// (8 lines vs 64/store). Per-j hoisted bases -> inner addr = base + imm-ish.
// attn reads these chunks contiguously via permuted per-lane offsets.
__global__ __launch_bounds__(256) void qkv_gemm(
    const u16* __restrict__ A, const u16* __restrict__ Bw,
    const float* __restrict__ bias,
    u16* __restrict__ Qb, u16* __restrict__ Kb, u16* __restrict__ VTb)
{
    __shared__ __align__(16) u16 Al[2][8 * 512];
    __shared__ __align__(16) u16 Bl[2][8 * 512];
    const int tid = threadIdx.x;
    const int lane = tid & 63;
    const int w = tid >> 6;
    const int la = lane & 15, qd = lane >> 4;
    const int m0 = blockIdx.y * 128;
    const int n0 = blockIdx.x * 128;
    const int wm = (w >> 1) * 64, wn = (w & 1) * 64;

    // tiled chunk bases: chunk linear = group*32 + kb, 512 u16 each
    const u16* Ag0 = A + ((size_t)((m0 >> 4) + 2 * w) * 32) * 512 + lane * 8;
    const u16* Ag1 = Ag0 + 32 * 512;
    const u16* Bg0 = Bw + ((size_t)((n0 >> 4) + 2 * w) * 32) * 512 + lane * 8;
    const u16* Bg1 = Bg0 + 32 * 512;

    auto stage = [&](int k0, int b) {
        const size_t ko = (size_t)(k0 >> 5) * 512;
        gl_lds16(Ag0 + ko, &Al[b][(2 * w) * 512]);
        gl_lds16(Ag1 + ko, &Al[b][(2 * w + 1) * 512]);
        gl_lds16(Bg0 + ko, &Bl[b][(2 * w) * 512]);
        gl_lds16(Bg1 + ko, &Bl[b][(2 * w + 1) * 512]);
    };

    f32x4 acc[4][4] = {};
    int buf = 0;
    stage(0, 0);

    for (int k0 = 0; k0 < 1024; k0 += 32) {
        __syncthreads();                       // drains prev prefetch (vmcnt 0)
        if (k0 + 32 < 1024) stage(k0 + 32, buf ^ 1);

        bf16x8 af[4], bfr[4];
#pragma unroll
        for (int i = 0; i < 4; i++)
            af[i] = *(const bf16x8*)&Al[buf][(((unsigned)wm >> 4) + i) * 512 + lane * 8];
#pragma unroll
        for (int j = 0; j < 4; j++)
            bfr[j] = *(const bf16x8*)&Bl[buf][(((unsigned)wn >> 4) + j) * 512 + lane * 8];
#pragma unroll
        for (int i = 0; i < 4; i++)
#pragma unroll
            for (int j = 0; j < 4; j++)
                acc[i][j] = __builtin_amdgcn_mfma_f32_16x16x32_bf16(
                    af[i], bfr[j], acc[i][j], 0, 0, 0);
        buf ^= 1;
    }

    // Epilogue. C/D: col = lane&15 (-> d), row = qd*4 + reg (-> n). Per-j the
    // target tensor t and per-thread d are FIXED; bases hoisted out of i/r.
    const int b_ = m0 >> 11;                         // batch (block-uniform)
    const int nb = (m0 & 2047) + wm;                 // token base (64-aligned)
#pragma unroll
    for (int j = 0; j < 4; j++) {
        const int colb = n0 + wn + j * 16;           // wave-uniform
        const int col = colb + la;
        const float bv = bias[col];
        const int t = colb >> 10;                    // wave-uniform selector
        const int hd = col & 1023, h = hd >> 6, d = hd & 63;
        const int bh = b_ * 16 + h;
        if (t == 0) {
            u16* QB = Qb + ((size_t)bh * 2048 + nb) * 64 + d;
#pragma unroll
            for (int i = 0; i < 4; i++)
#pragma unroll
                for (int r = 0; r < 4; r++)
                    QB[(i * 16 + qd * 4 + r) * 64] = f2bf(acc[i][j][r] + bv);
        } else if (t == 1) {
            u16* KB = Kb + (size_t)bh * 131072
                    + (size_t)((nb >> 4) * 2 + (d >> 5)) * 512 + (d & 31);
#pragma unroll
            for (int i = 0; i < 4; i++)
#pragma unroll
                for (int r = 0; r < 4; r++)
                    KB[i * 1024 + (qd * 4 + r) * 32] = f2bf(acc[i][j][r] + bv);
        } else {
            u16* VB = VTb + (size_t)bh * 131072
                    + (size_t)(d >> 4) * 32768 + (d & 15) * 32;
#pragma unroll
            for (int i = 0; i < 4; i++)
#pragma unroll
                for (int r = 0; r < 4; r++)
                    VB[((nb >> 5) + (i >> 1)) * 512 + (i & 1) * 16 + qd * 4 + r]
                        = f2bf(acc[i][j][r] + bv);
        }
    }
}

// ---------------- proj GEMM, BK=64; A and B both from tiled layouts ----------
// M=4096, N=1024, K=1024; tile 128x64, 2-D grid 16x32 (r10, kept).
__global__ __launch_bounds__(256) void proj_gemm(
    const u16* __restrict__ A, const u16* __restrict__ Bw,
    const float* __restrict__ bias, float* __restrict__ Out)
{
    __shared__ __align__(16) u16 Al[2][16 * 512];   // 32 KB
    __shared__ __align__(16) u16 Bl[2][8 * 512];    // 16 KB
    const int tid = threadIdx.x;
    const int lane = tid & 63;
    const int w = tid >> 6;
    const int la = lane & 15, qd = lane >> 4;
    const int K = 1024;
    const int m0 = blockIdx.y * 128;
    const int n0 = blockIdx.x * 64;
    const int wm = (w >> 1) * 64, wn = (w & 1) * 32;

    const u16* Ab[4];
#pragma unroll
    for (int t = 0; t < 4; t++) {
        const int ck = 4 * w + t, g = ck >> 1, h = ck & 1;
        Ab[t] = A + (((size_t)(m0 >> 4) + g) * 32 + h) * 512 + lane * 8;
    }
    const u16* Bg = Bw + ((size_t)((n0 >> 4) + w) * 32) * 512 + lane * 8;

    auto stage = [&](int k0, int b) {
#pragma unroll
        for (int t = 0; t < 4; t++)
            gl_lds16(Ab[t] + (size_t)(k0 >> 5) * 512, &Al[b][(4 * w + t) * 512]);
#pragma unroll
        for (int t = 0; t < 2; t++)
            gl_lds16(Bg + (size_t)((k0 >> 5) + t) * 512, &Bl[b][(2 * w + t) * 512]);
    };

    f32x4 acc[4][2] = {};
    int buf = 0;
    stage(0, 0);

    for (int k0 = 0; k0 < K; k0 += 64) {
        __syncthreads();                       // drains prev prefetch (vmcnt 0)
        if (k0 + 64 < K) stage(k0 + 64, buf ^ 1);

        bf16x8 af[4][2], bfr[2][2];
#pragma unroll
        for (int i = 0; i < 4; i++) {
            const int g = ((unsigned)wm >> 4) + i;
#pragma unroll
            for (int h = 0; h < 2; h++)
                af[i][h] = *(const bf16x8*)&Al[buf][(g * 2 + h) * 512 + lane * 8];
        }
#pragma unroll
        for (int j = 0; j < 2; j++) {
            const int g = ((unsigned)wn >> 4) + j;
#pragma unroll
            for (int h = 0; h < 2; h++)
                bfr[j][h] = *(const bf16x8*)&Bl[buf][(g * 2 + h) * 512 + lane * 8];
        }
#pragma unroll
        for (int i = 0; i < 4; i++)
#pragma unroll
            for (int j = 0; j < 2; j++) {
                f32x4 c = acc[i][j];
                c = __builtin_amdgcn_mfma_f32_16x16x32_bf16(af[i][0], bfr[j][0], c, 0, 0, 0);
                c = __builtin_amdgcn_mfma_f32_16x16x32_bf16(af[i][1], bfr[j][1], c, 0, 0, 0);
                acc[i][j] = c;
            }
        buf ^= 1;
    }

    // Epilogue (fp32 out + bias). C/D layout: col = lane&15, row = qd*4 + r.
#pragma unroll
    for (int j = 0; j < 2; j++) {
        const int col = n0 + wn + j * 16 + la;
        const float bv = bias[col];
#pragma unroll
        for (int i = 0; i < 4; i++)
#pragma unroll
            for (int r = 0; r < 4; r++) {
                const int row = m0 + wm + i * 16 + qd * 4 + r;
                Out[(size_t)row * 1024 + col] = acc[i][j][r] + bv;
            }
    }
}

// ---------------- causal flash attention, LDS-staged, j-step 128 -------------
// r11: K/V chunks are row-major interior; staging uses PERMUTED per-lane
// source offsets (lane l reads interior (l&15)*32 + (l>>4)*8) — the 64
// addresses tile the contiguous 1KB chunk, so coalescing == r10's identity
// order, but the producer's writes stay cheap. LDS image bit-identical.
// Ob written in proj-A-tiled layout (r10, kept).
__global__ __launch_bounds__(256) void attn_k(
    const u16* __restrict__ Qb, const u16* __restrict__ Kb,
    const u16* __restrict__ VTb, u16* __restrict__ Ob)
{
    __shared__ __align__(16) u16 Kl[2][16 * 512];   // 32 KB: chunk ck=c*2+h
    __shared__ __align__(16) u16 Vl[2][16 * 512];   // 32 KB: chunk cv=c2*4+kc
    __shared__ __align__(16) u16 Pl[4][16 * 72];    // per-wave P, stride 72
    const int bh = blockIdx.x & 31;
    const int pair = blockIdx.x >> 5;               // 0..15
    const int tid = threadIdx.x;
    const int lane = tid & 63;
    const int w = tid >> 6;
    const int la = lane & 15, qd = lane >> 4;

    // permuted in-chunk offset: lane l -> row-major interior (n-or-d &15)*32 + k*8
    const int perm = (lane & 15) * 32 + (lane >> 4) * 8;
    const u16* Kbh = Kb + (size_t)bh * 131072 + perm;
    const u16* Vbh = VTb + (size_t)bh * 131072 + perm;
    u16* Pw = &Pl[w][0];

    // stage: wave w stages K chunks 4w..4w+3, V chunks 4w..4w+3 of a j128 tile
    // K global chunk = (j0>>3)+ck ; V global chunk = (ck>>2)*64 + (j0>>5)+(ck&3)
    auto stage = [&](int j0, int b) {
#pragma unroll
        for (int t = 0; t < 4; t++) {
            const int ck = 4 * w + t;
            gl_lds16(Kbh + (size_t)((j0 >> 3) + ck) * 512, &Kl[b][ck * 512]);
            gl_lds16(Vbh + (size_t)((ck >> 2) * 64 + (j0 >> 5) + (ck & 3)) * 512,
                     &Vl[b][ck * 512]);
        }
    };

    int buf = 0;
    stage(0, 0);                                    // prologue for first tile

    for (int half = 0; half < 2; half++) {
        const int tile = (half == 0) ? pair : 31 - pair;
        const int q0 = tile * 64 + w * 16;
        const int jmax = (tile >> 1) * 128;         // last j128-tile start
        const int qrow = q0 + la;                   // this lane's q-row

        const u16* Qp = Qb + ((size_t)bh * 2048 + q0 + la) * 64 + qd * 8;
        const bf16x8 qf0 = *(const bf16x8*)Qp;
        const bf16x8 qf1 = *(const bf16x8*)(Qp + 32);

        f32x4 o[4] = {};
        float lsum = 0.f;

        for (int j0 = 0; j0 <= jmax; j0 += 128) {
            __syncthreads();   // drains prev prefetch (vmcnt 0, all waves)

            const int nj = (j0 + 128 <= jmax) ? (j0 + 128) : ((half == 0) ? 0 : -1);
            if (nj >= 0) stage(nj, buf ^ 1);

            // S^T = K Q^T : 8 j-subtiles; D[row=j (qd*4+r), col=q (la)]
            f32x4 s[8];
#pragma unroll
            for (int c = 0; c < 8; c++) {
                f32x4 z = {};
                const bf16x8 kf0 = *(const bf16x8*)&Kl[buf][(c * 2 + 0) * 512 + lane * 8];
                const bf16x8 kf1 = *(const bf16x8*)&Kl[buf][(c * 2 + 1) * 512 + lane * 8];
                z = __builtin_amdgcn_mfma_f32_16x16x32_bf16(kf0, qf0, z, 0, 0, 0);
                z = __builtin_amdgcn_mfma_f32_16x16x32_bf16(kf1, qf1, z, 0, 0, 0);
                s[c] = z;
            }

            // p = exp2(s * SL); causal mask only on the diagonal-containing tile
            if (j0 == jmax) {
#pragma unroll
                for (int c = 0; c < 8; c++)
#pragma unroll
                    for (int r = 0; r < 4; r++) {
                        const int j = j0 + c * 16 + qd * 4 + r;
                        float v = s[c][r] * SL_F;
                        v = (j > qrow) ? -1e30f : v;
                        s[c][r] = __builtin_amdgcn_exp2f(v);
                    }
            } else {
#pragma unroll
                for (int c = 0; c < 8; c++)
#pragma unroll
                    for (int r = 0; r < 4; r++)
                        s[c][r] = __builtin_amdgcn_exp2f(s[c][r] * SL_F);
            }
#pragma unroll
            for (int c = 0; c < 8; c++)
#pragma unroll
                for (int r = 0; r < 4; r++)
                    lsum += s[c][r];

            // PV in two j-64 halves, reusing the per-wave P buffer (same-wave
            // DS ops are in-order: the hh=1 writes cannot pass hh=0 reads)
#pragma unroll
            for (int hh = 0; hh < 2; hh++) {
#pragma unroll
                for (int c = 0; c < 4; c++) {
                    uint2 pw;
                    pw.x = pack2bf(s[hh * 4 + c][0], s[hh * 4 + c][1]);
                    pw.y = pack2bf(s[hh * 4 + c][2], s[hh * 4 + c][3]);
                    *(uint2*)&Pw[la * 72 + c * 16 + qd * 4] = pw;
                }
                const bf16x8 pf0 = *(const bf16x8*)&Pw[la * 72 + qd * 8];
                const bf16x8 pf1 = *(const bf16x8*)&Pw[la * 72 + 32 + qd * 8];
#pragma unroll
                for (int c2 = 0; c2 < 4; c2++) {
                    const bf16x8 vf0 = *(const bf16x8*)&Vl[buf][(c2 * 4 + hh * 2 + 0) * 512 + lane * 8];
                    const bf16x8 vf1 = *(const bf16x8*)&Vl[buf][(c2 * 4 + hh * 2 + 1) * 512 + lane * 8];
                    o[c2] = __builtin_amdgcn_mfma_f32_16x16x32_bf16(pf0, vf0, o[c2], 0, 0, 0);
                    o[c2] = __builtin_amdgcn_mfma_f32_16x16x32_bf16(pf1, vf1, o[c2], 0, 0, 0);
                }
            }
            buf ^= 1;
        }

        // reduce l across the 4 quads (lane la holds row la's partials)
        lsum += __shfl_xor(lsum, 16, 64);
        lsum += __shfl_xor(lsum, 32, 64);
        float rinv[4];
#pragma unroll
        for (int r = 0; r < 4; r++)
            rinv[r] = 1.0f / __shfl(lsum, qd * 4 + r, 64);

        // write Ob in proj-A-tiled layout: m = bh*128 + (q0>>4) (wave-uniform),
        // k = (qd*4+r)*64 + c2*16 + la
        const int m = bh * 128 + (q0 >> 4);
        u16* Ot = Ob + ((size_t)(m >> 4) * 32) * 512;
        const int mm = m & 15;
#pragma unroll
        for (int c2 = 0; c2 < 4; c2++)
#pragma unroll
            for (int r = 0; r < 4; r++) {
                const int kk5 = (qd * 4 + r) * 2 + (c2 >> 1);
                const int s3 = (c2 * 2 + (la >> 3)) & 3;
                Ot[(size_t)kk5 * 512 + (mm + 16 * s3) * 8 + (la & 7)] =
                    f2bf(o[c2][r] * rinv[r]);
            }
    }
}

// ---------------- launch -----------------------------------------------------
extern "C" void kernel_launch(void* const* d_in, const int* in_sizes, int n_in,
                              void* d_out, int out_size, void* d_ws, size_t ws_size,
                              hipStream_t stream)
{
    const float* x     = (const float*)d_in[0];
    // d_in[1] = attention_mask: structurally causal tril; enforced analytically.
    const float* wqkv  = (const float*)d_in[2];
    const float* bqkv  = (const float*)d_in[3];
    const float* wproj = (const float*)d_in[4];
    const float* bproj = (const float*)d_in[5];
    float* out = (float*)d_out;

    // workspace layout (u16 units), ~50 MB total
    u16* ws     = (u16*)d_ws;
    u16* xb     = ws;                       // 4096*1024   (tiled)
    u16* wqkvb  = xb + 4096 * 1024;         // 3072*1024   (tiled)
    u16* wprojb = wqkvb + 3072 * 1024;      // 1024*1024   (tiled)
    u16* Qb     = wprojb + 1024 * 1024;     // 32*2048*64  [B,H,N,D] row-major
    u16* Kb     = Qb + 32 * 2048 * 64;      // 32*256 chunks (row-major interior)
    u16* VTb    = Kb + 32 * 2048 * 64;      // 32*256 chunks (row-major interior)
    u16* Ob     = VTb + 32 * 2048 * 64;     // 8192 chunks (proj-A tiled)

    convert_k<<<dim3(4096), dim3(256), 0, stream>>>(
        x, wqkv, wproj, xb, wqkvb, wprojb);

    // qkv: 128x128 tile, 2-D grid 24x32 (XCD banding + balanced scatter)
    qkv_gemm<<<dim3(24, 32), dim3(256), 0, stream>>>(
        xb, wqkvb, bqkv, Qb, Kb, VTb);

    attn_k<<<dim3(512), dim3(256), 0, stream>>>(Qb, Kb, VTb, Ob);

    // proj: 128x64 tile, BK=64, 2-D grid 16x32
    proj_gemm<<<dim3(16, 32), dim3(256), 0, stream>>>(
        Ob, wprojb, bproj, out);
}

// Round 12
// 188.400 us; speedup vs baseline: 1.1257x; 1.0012x over previous
//
#include <hip/hip_runtime.h>
#include <hip/hip_bf16.h>
#include <stdint.h>

// Problem constants (B=2, N=2048, C=1024, H=16, D=64)
#define SL_F 0.18033688011112043f   // SCALE * log2(e): softmax in exp2 domain

typedef unsigned short u16;
typedef unsigned int u32;
typedef __attribute__((ext_vector_type(8))) short bf16x8;   // 8 bf16 = 4 VGPRs
typedef __attribute__((ext_vector_type(4))) float f32x4;

__device__ __forceinline__ u16 f2bf(float f) {
    union { float f; u32 u; } v; v.f = f;
    return (u16)((v.u + 0x7fffu + ((v.u >> 16) & 1u)) >> 16);  // RNE
}
__device__ __forceinline__ u32 pack2bf(float a, float b) {
    union { __hip_bfloat162 h; u32 u; } p;
    p.h = __float22bfloat162_rn(make_float2(a, b));
    return p.u;
}

// async global->LDS, 16B per lane; LDS dest = wave-uniform base + lane*16.
// Global src is PER-LANE: coalescing needs the 64-address SET contiguous,
// not lane-identity order (r11 verified: permuted-slot chunks).
__device__ __forceinline__ void gl_lds16(const u16* g, u16* l) {
    __builtin_amdgcn_global_load_lds(
        (const __attribute__((address_space(1))) u32*)g,
        (__attribute__((address_space(3))) u32*)l, 16, 0, 0);
}

// ---------------- fp32 -> bf16 TILED conversion of x, w_qkv, w_proj ---------
// Fragment-tiled layout (r9, VERIFIED): chunk(g,kb)=1KB, slot order =
// gl_lds16 deposit. Staging = chunk + lane*16 (8 full 128B lines/instr).
__global__ __launch_bounds__(256) void convert_k(
    const float* __restrict__ x, const float* __restrict__ w1,
    const float* __restrict__ w2,
    u16* __restrict__ xb, u16* __restrict__ w1b, u16* __restrict__ w2b)
{
    const int t = blockIdx.x * 256 + threadIdx.x;   // global slot id
    const int XA = 524288, XW1 = 393216;            // slots: 4096*128, 3072*128
    const float* src; u16* dst; int s;
    if (t < XA)            { src = x;  dst = xb;  s = t; }
    else if (t < XA + XW1) { src = w1; dst = w1b; s = t - XA; }
    else                   { src = w2; dst = w2b; s = t - XA - XW1; }
    const int c = s >> 6;                    // chunk (wave-uniform)
    const int u = s & 63;
    const int l = (u >> 2) + 16 * (u & 3);   // slot within chunk
    const int g = c >> 5, kb = c & 31;
    const int row = g * 16 + (l & 15);
    const int k0 = kb * 32 + (l >> 4) * 8;
    const float4 v0 = *(const float4*)&src[(size_t)row * 1024 + k0];
    const float4 v1 = *(const float4*)&src[(size_t)row * 1024 + k0 + 4];
    uint4 o;
    o.x = pack2bf(v0.x, v0.y); o.y = pack2bf(v0.z, v0.w);
    o.z = pack2bf(v1.x, v1.y); o.w = pack2bf(v1.z, v1.w);
    *(uint4*)&dst[((size_t)c * 64 + l) * 8] = o;
}

// ---------------- QKV GEMM: out[m,n] = sum_k A[m,k]*W[n,k] + bias ------------
// r6 proven body + 24x32 grid + r9 tiled A/B staging + r11 row-major-interior
// K/V^T chunks (all verified). r12: Q is PRE-SCALED by SL_F (Q only feeds
// QK^T; folds the softmax exp2-domain scale into the GEMM epilogue, deleting
// 32 v_mul per attn iter per wave).
__global__ __launch_bounds__(256) void qkv_gemm(
    const u16* __restrict__ A, const u16* __restrict__ Bw,
    const float* __restrict__ bias,
    u16* __restrict__ Qb, u16* __restrict__ Kb, u16* __restrict__ VTb)
{
    __shared__ __align__(16) u16 Al[2][8 * 512];
    __shared__ __align__(16) u16 Bl[2][8 * 512];
    const int tid = threadIdx.x;
    const int lane = tid & 63;
    const int w = tid >> 6;
    const int la = lane & 15, qd = lane >> 4;
    const int m0 = blockIdx.y * 128;
    const int n0 = blockIdx.x * 128;
    const int wm = (w >> 1) * 64, wn = (w & 1) * 64;

    const u16* Ag0 = A + ((size_t)((m0 >> 4) + 2 * w) * 32) * 512 + lane * 8;
    const u16* Ag1 = Ag0 + 32 * 512;
    const u16* Bg0 = Bw + ((size_t)((n0 >> 4) + 2 * w) * 32) * 512 + lane * 8;
    const u16* Bg1 = Bg0 + 32 * 512;

    auto stage = [&](int k0, int b) {
        const size_t ko = (size_t)(k0 >> 5) * 512;
        gl_lds16(Ag0 + ko, &Al[b][(2 * w) * 512]);
        gl_lds16(Ag1 + ko, &Al[b][(2 * w + 1) * 512]);
        gl_lds16(Bg0 + ko, &Bl[b][(2 * w) * 512]);
        gl_lds16(Bg1 + ko, &Bl[b][(2 * w + 1) * 512]);
    };

    f32x4 acc[4][4] = {};
    int buf = 0;
    stage(0, 0);

    for (int k0 = 0; k0 < 1024; k0 += 32) {
        __syncthreads();                       // drains prev prefetch (vmcnt 0)
        if (k0 + 32 < 1024) stage(k0 + 32, buf ^ 1);

        bf16x8 af[4], bfr[4];
#pragma unroll
        for (int i = 0; i < 4; i++)
            af[i] = *(const bf16x8*)&Al[buf][(((unsigned)wm >> 4) + i) * 512 + lane * 8];
#pragma unroll
        for (int j = 0; j < 4; j++)
            bfr[j] = *(const bf16x8*)&Bl[buf][(((unsigned)wn >> 4) + j) * 512 + lane * 8];
#pragma unroll
        for (int i = 0; i < 4; i++)
#pragma unroll
            for (int j = 0; j < 4; j++)
                acc[i][j] = __builtin_amdgcn_mfma_f32_16x16x32_bf16(
                    af[i], bfr[j], acc[i][j], 0, 0, 0);
        buf ^= 1;
    }

    // Epilogue. C/D: col = lane&15 (-> d), row = qd*4 + reg (-> n).
    const int b_ = m0 >> 11;                         // batch (block-uniform)
    const int nb = (m0 & 2047) + wm;                 // token base (64-aligned)
#pragma unroll
    for (int j = 0; j < 4; j++) {
        const int colb = n0 + wn + j * 16;           // wave-uniform
        const int col = colb + la;
        const float bv = bias[col];
        const int t = colb >> 10;                    // wave-uniform selector
        const int hd = col & 1023, h = hd >> 6, d = hd & 63;
        const int bh = b_ * 16 + h;
        if (t == 0) {
            u16* QB = Qb + ((size_t)bh * 2048 + nb) * 64 + d;
#pragma unroll
            for (int i = 0; i < 4; i++)
#pragma unroll
                for (int r = 0; r < 4; r++)
                    QB[(i * 16 + qd * 4 + r) * 64] =
                        f2bf((acc[i][j][r] + bv) * SL_F);   // pre-scaled Q
        } else if (t == 1) {
            u16* KB = Kb + (size_t)bh * 131072
                    + (size_t)((nb >> 4) * 2 + (d >> 5)) * 512 + (d & 31);
#pragma unroll
            for (int i = 0; i < 4; i++)
#pragma unroll
                for (int r = 0; r < 4; r++)
                    KB[i * 1024 + (qd * 4 + r) * 32] = f2bf(acc[i][j][r] + bv);
        } else {
            u16* VB = VTb + (size_t)bh * 131072
                    + (size_t)(d >> 4) * 32768 + (d & 15) * 32;
#pragma unroll
            for (int i = 0; i < 4; i++)
#pragma unroll
                for (int r = 0; r < 4; r++)
                    VB[((nb >> 5) + (i >> 1)) * 512 + (i & 1) * 16 + qd * 4 + r]
                        = f2bf(acc[i][j][r] + bv);
        }
    }
}

// ---------------- proj GEMM, BK=64; A and B both from tiled layouts ----------
// (r10/r11, verified; unchanged)
__global__ __launch_bounds__(256) void proj_gemm(
    const u16* __restrict__ A, const u16* __restrict__ Bw,
    const float* __restrict__ bias, float* __restrict__ Out)
{
    __shared__ __align__(16) u16 Al[2][16 * 512];   // 32 KB
    __shared__ __align__(16) u16 Bl[2][8 * 512];    // 16 KB
    const int tid = threadIdx.x;
    const int lane = tid & 63;
    const int w = tid >> 6;
    const int la = lane & 15, qd = lane >> 4;
    const int K = 1024;
    const int m0 = blockIdx.y * 128;
    const int n0 = blockIdx.x * 64;
    const int wm = (w >> 1) * 64, wn = (w & 1) * 32;

    const u16* Ab[4];
#pragma unroll
    for (int t = 0; t < 4; t++) {
        const int ck = 4 * w + t, g = ck >> 1, h = ck & 1;
        Ab[t] = A + (((size_t)(m0 >> 4) + g) * 32 + h) * 512 + lane * 8;
    }
    const u16* Bg = Bw + ((size_t)((n0 >> 4) + w) * 32) * 512 + lane * 8;

    auto stage = [&](int k0, int b) {
#pragma unroll
        for (int t = 0; t < 4; t++)
            gl_lds16(Ab[t] + (size_t)(k0 >> 5) * 512, &Al[b][(4 * w + t) * 512]);
#pragma unroll
        for (int t = 0; t < 2; t++)
            gl_lds16(Bg + (size_t)((k0 >> 5) + t) * 512, &Bl[b][(2 * w + t) * 512]);
    };

    f32x4 acc[4][2] = {};
    int buf = 0;
    stage(0, 0);

    for (int k0 = 0; k0 < K; k0 += 64) {
        __syncthreads();                       // drains prev prefetch (vmcnt 0)
        if (k0 + 64 < K) stage(k0 + 64, buf ^ 1);

        bf16x8 af[4][2], bfr[2][2];
#pragma unroll
        for (int i = 0; i < 4; i++) {
            const int g = ((unsigned)wm >> 4) + i;
#pragma unroll
            for (int h = 0; h < 2; h++)
                af[i][h] = *(const bf16x8*)&Al[buf][(g * 2 + h) * 512 + lane * 8];
        }
#pragma unroll
        for (int j = 0; j < 2; j++) {
            const int g = ((unsigned)wn >> 4) + j;
#pragma unroll
            for (int h = 0; h < 2; h++)
                bfr[j][h] = *(const bf16x8*)&Bl[buf][(g * 2 + h) * 512 + lane * 8];
        }
#pragma unroll
        for (int i = 0; i < 4; i++)
#pragma unroll
            for (int j = 0; j < 2; j++) {
                f32x4 c = acc[i][j];
                c = __builtin_amdgcn_mfma_f32_16x16x32_bf16(af[i][0], bfr[j][0], c, 0, 0, 0);
                c = __builtin_amdgcn_mfma_f32_16x16x32_bf16(af[i][1], bfr[j][1], c, 0, 0, 0);
                acc[i][j] = c;
            }
        buf ^= 1;
    }

    // Epilogue (fp32 out + bias). C/D layout: col = lane&15, row = qd*4 + r.
#pragma unroll
    for (int j = 0; j < 2; j++) {
        const int col = n0 + wn + j * 16 + la;
        const float bv = bias[col];
#pragma unroll
        for (int i = 0; i < 4; i++)
#pragma unroll
            for (int r = 0; r < 4; r++) {
                const int row = m0 + wm + i * 16 + qd * 4 + r;
                Out[(size_t)row * 1024 + col] = acc[i][j][r] + bv;
            }
    }
}

// ---------------- causal flash attention, Q-block 128, 8 waves ---------------
// r12: 512-thread blocks — 8 waves x 16 q-rows = 128 CONTIGUOUS q-rows share
// ONE K/V staging stream (r11 measured attn pinned at the ~6.3 TB/s staging
// rate with 278MB staged; this halves it to 139MB). For Q-tile T all j-tiles
// 0..T are needed by every wave (full activity; diagonal masking per-lane).
// Block does tiles {T, 15-T} -> uniform 17 iters. Grid 256 = 32 bh (low bits,
// XCD affinity) x 8 pairs; 1 block/CU, 8 waves/CU (occ 25%). Q pre-scaled by
// SL_F in qkv -> softmax is exp2 directly. K/V tiled chunks + permuted-lane
// staging (r11). Ob in proj-A-tiled layout (r10).
__global__ __launch_bounds__(512) void attn_k(
    const u16* __restrict__ Qb, const u16* __restrict__ Kb,
    const u16* __restrict__ VTb, u16* __restrict__ Ob)
{
    __shared__ __align__(16) u16 Kl[2][16 * 512];   // 32 KB: chunk ck=c*2+h
    __shared__ __align__(16) u16 Vl[2][16 * 512];   // 32 KB: chunk cv=c2*4+kc
    __shared__ __align__(16) u16 Pl[8][16 * 72];    // per-wave P, stride 72
    const int bh = blockIdx.x & 31;
    const int pairT = blockIdx.x >> 5;              // 0..7
    const int tid = threadIdx.x;
    const int lane = tid & 63;
    const int w = tid >> 6;                         // 0..7
    const int la = lane & 15, qd = lane >> 4;

    // permuted in-chunk offset: lane l -> row-major interior (l&15)*32 + (l>>4)*8
    const int perm = (lane & 15) * 32 + (lane >> 4) * 8;
    const u16* Kbh = Kb + (size_t)bh * 131072 + perm;
    const u16* Vbh = VTb + (size_t)bh * 131072 + perm;
    u16* Pw = &Pl[w][0];

    // stage: wave w stages K chunks {2w,2w+1}, V chunks {2w,2w+1} of a j128
    // tile. K global chunk = (j0>>3)+ck ; V global = (ck>>2)*64+(j0>>5)+(ck&3)
    auto stage = [&](int j0, int b) {
#pragma unroll
        for (int t = 0; t < 2; t++) {
            const int ck = 2 * w + t;
            gl_lds16(Kbh + (size_t)((j0 >> 3) + ck) * 512, &Kl[b][ck * 512]);
            gl_lds16(Vbh + (size_t)((ck >> 2) * 64 + (j0 >> 5) + (ck & 3)) * 512,
                     &Vl[b][ck * 512]);
        }
    };

    int buf = 0;
    stage(0, 0);                                    // prologue for first tile

    for (int half = 0; half < 2; half++) {
        const int tile = (half == 0) ? pairT : 15 - pairT;
        const int q0 = tile * 128 + w * 16;
        const int jmax = tile * 128;                // last (diagonal) j128-tile
        const int qrow = q0 + la;                   // this lane's q-row

        const u16* Qp = Qb + ((size_t)bh * 2048 + q0 + la) * 64 + qd * 8;
        const bf16x8 qf0 = *(const bf16x8*)Qp;
        const bf16x8 qf1 = *(const bf16x8*)(Qp + 32);

        f32x4 o[4] = {};
        float lsum = 0.f;

        for (int j0 = 0; j0 <= jmax; j0 += 128) {
            __syncthreads();   // drains prev prefetch (vmcnt 0, all waves)

            const int nj = (j0 + 128 <= jmax) ? (j0 + 128) : ((half == 0) ? 0 : -1);
            if (nj >= 0) stage(nj, buf ^ 1);

            // S^T = K Q'^T (Q pre-scaled): 8 j-subtiles; D[row=j, col=q (la)]
            f32x4 s[8];
#pragma unroll
            for (int c = 0; c < 8; c++) {
                f32x4 z = {};
                const bf16x8 kf0 = *(const bf16x8*)&Kl[buf][(c * 2 + 0) * 512 + lane * 8];
                const bf16x8 kf1 = *(const bf16x8*)&Kl[buf][(c * 2 + 1) * 512 + lane * 8];
                z = __builtin_amdgcn_mfma_f32_16x16x32_bf16(kf0, qf0, z, 0, 0, 0);
                z = __builtin_amdgcn_mfma_f32_16x16x32_bf16(kf1, qf1, z, 0, 0, 0);
                s[c] = z;
            }

            // p = exp2(s); causal mask only on the diagonal tile
            if (j0 == jmax) {
#pragma unroll
                for (int c = 0; c < 8; c++)
#pragma unroll
                    for (int r = 0; r < 4; r++) {
                        const int j = j0 + c * 16 + qd * 4 + r;
                        float v = s[c][r];
                        v = (j > qrow) ? -1e30f : v;
                        s[c][r] = __builtin_amdgcn_exp2f(v);
                    }
            } else {
#pragma unroll
                for (int c = 0; c < 8; c++)
#pragma unroll
                    for (int r = 0; r < 4; r++)
                        s[c][r] = __builtin_amdgcn_exp2f(s[c][r]);
            }
#pragma unroll
            for (int c = 0; c < 8; c++)
#pragma unroll
                for (int r = 0; r < 4; r++)
                    lsum += s[c][r];

            // PV in two j-64 halves, reusing the per-wave P buffer (same-wave
            // DS ops are in-order: the hh=1 writes cannot pass hh=0 reads)
#pragma unroll
            for (int hh = 0; hh < 2; hh++) {
#pragma unroll
                for (int c = 0; c < 4; c++) {
                    uint2 pw;
                    pw.x = pack2bf(s[hh * 4 + c][0], s[hh * 4 + c][1]);
                    pw.y = pack2bf(s[hh * 4 + c][2], s[hh * 4 + c][3]);
                    *(uint2*)&Pw[la * 72 + c * 16 + qd * 4] = pw;
                }
                const bf16x8 pf0 = *(const bf16x8*)&Pw[la * 72 + qd * 8];
                const bf16x8 pf1 = *(const bf16x8*)&Pw[la * 72 + 32 + qd * 8];
#pragma unroll
                for (int c2 = 0; c2 < 4; c2++) {
                    const bf16x8 vf0 = *(const bf16x8*)&Vl[buf][(c2 * 4 + hh * 2 + 0) * 512 + lane * 8];
                    const bf16x8 vf1 = *(const bf16x8*)&Vl[buf][(c2 * 4 + hh * 2 + 1) * 512 + lane * 8];
                    o[c2] = __builtin_amdgcn_mfma_f32_16x16x32_bf16(pf0, vf0, o[c2], 0, 0, 0);
                    o[c2] = __builtin_amdgcn_mfma_f32_16x16x32_bf16(pf1, vf1, o[c2], 0, 0, 0);
                }
            }
            buf ^= 1;
        }

        // reduce l across the 4 quads (lane la holds row la's partials)
        lsum += __shfl_xor(lsum, 16, 64);
        lsum += __shfl_xor(lsum, 32, 64);
        float rinv[4];
#pragma unroll
        for (int r = 0; r < 4; r++)
            rinv[r] = 1.0f / __shfl(lsum, qd * 4 + r, 64);

        // write Ob in proj-A-tiled layout: m = bh*128 + tile*8 + w (uniform),
        // k = (qd*4+r)*64 + c2*16 + la
        const int m = bh * 128 + (q0 >> 4);
        u16* Ot = Ob + ((size_t)(m >> 4) * 32) * 512;
        const int mm = m & 15;
#pragma unroll
        for (int c2 = 0; c2 < 4; c2++)
#pragma unroll
            for (int r = 0; r < 4; r++) {
                const int kk5 = (qd * 4 + r) * 2 + (c2 >> 1);
                const int s3 = (c2 * 2 + (la >> 3)) & 3;
                Ot[(size_t)kk5 * 512 + (mm + 16 * s3) * 8 + (la & 7)] =
                    f2bf(o[c2][r] * rinv[r]);
            }
    }
}

// ---------------- launch -----------------------------------------------------
extern "C" void kernel_launch(void* const* d_in, const int* in_sizes, int n_in,
                              void* d_out, int out_size, void* d_ws, size_t ws_size,
                              hipStream_t stream)
{
    const float* x     = (const float*)d_in[0];
    // d_in[1] = attention_mask: structurally causal tril; enforced analytically.
    const float* wqkv  = (const float*)d_in[2];
    const float* bqkv  = (const float*)d_in[3];
    const float* wproj = (const float*)d_in[4];
    const float* bproj = (const float*)d_in[5];
    float* out = (float*)d_out;

    // workspace layout (u16 units), ~50 MB total
    u16* ws     = (u16*)d_ws;
    u16* xb     = ws;                       // 4096*1024   (tiled)
    u16* wqkvb  = xb + 4096 * 1024;         // 3072*1024   (tiled)
    u16* wprojb = wqkvb + 3072 * 1024;      // 1024*1024   (tiled)
    u16* Qb     = wprojb + 1024 * 1024;     // 32*2048*64  [B,H,N,D] row-major (pre-scaled by SL_F)
    u16* Kb     = Qb + 32 * 2048 * 64;      // 32*256 chunks (row-major interior)
    u16* VTb    = Kb + 32 * 2048 * 64;      // 32*256 chunks (row-major interior)
    u16* Ob     = VTb + 32 * 2048 * 64;     // 8192 chunks (proj-A tiled)

    convert_k<<<dim3(4096), dim3(256), 0, stream>>>(
        x, wqkv, wproj, xb, wqkvb, wprojb);

    // qkv: 128x128 tile, 2-D grid 24x32 (XCD banding + balanced scatter)
    qkv_gemm<<<dim3(24, 32), dim3(256), 0, stream>>>(
        xb, wqkvb, bqkv, Qb, Kb, VTb);

    // attn: Q-block 128, 8 waves, 256 blocks (32 bh x 8 pairs)
    attn_k<<<dim3(256), dim3(512), 0, stream>>>(Qb, Kb, VTb, Ob);

    // proj: 128x64 tile, BK=64, 2-D grid 16x32
    proj_gemm<<<dim3(16, 32), dim3(256), 0, stream>>>(
        Ob, wprojb, bproj, out);
}